// Round 2
// 368.720 us; speedup vs baseline: 1.1811x; 1.1811x over previous
//
#include <hip/hip_runtime.h>

typedef _Float16 h2_t __attribute__((ext_vector_type(2)));

#define DI __device__ __forceinline__

#if __has_builtin(__builtin_amdgcn_sched_barrier)
#define SCHED_FENCE() __builtin_amdgcn_sched_barrier(0)
#else
#define SCHED_FENCE()
#endif

constexpr int PA = 98;           // staged tile pitch (halfs): 49 dwords, odd
constexpr int PB = 66;           // hb pitch (halfs): 33 dwords, odd
constexpr int TILE = 64 * PA;    // staged x/y tile: 64 rows x 96 cols (6272 h)
constexpr int PLANE = 64 * PB;   // one hb plane: 64 cols x 64 rows (4224 h)
constexpr float kC1 = 1.0e-4f;   // (0.01*1)^2
constexpr float kC2 = 9.0e-4f;   // (0.03*1)^2
constexpr float kALPHA = 0.025f;

DI float rcp_fast(float v) { return __builtin_amdgcn_rcpf(v); }

DI float fdot2f(h2_t a, h2_t b, float c) {
#if __has_builtin(__builtin_amdgcn_fdot2)
  return __builtin_amdgcn_fdot2(a, b, c, false);   // v_dot2_f32_f16
#else
  return c + (float)(a.x) * (float)(b.x) + (float)(a.y) * (float)(b.y);
#endif
}

DI h2_t ldh2(const _Float16* __restrict__ p) {
  return *reinterpret_cast<const h2_t*>(p);
}
DI h2_t w2h(unsigned u) { return __builtin_bit_cast(h2_t, u); }
DI h2_t pkabs(h2_t v) {
  unsigned u = __builtin_bit_cast(unsigned, v) & 0x7FFF7FFFu;
  return __builtin_bit_cast(h2_t, u);
}

// ---- horizontal conv, TWO fields per pass -> 2-plane hb ----
// Thread item = 1 row x 8 CONSECUTIVE cols. Even cols use E table, odd use O,
// both at uniform addresses -> s_load -> SGPR weights.
// PASS 0: fields {x, y}.  PASS 1: fields {x^2+y^2, x*y}  (conv is linear, and
// cs only consumes E[x^2]+E[y^2], so one conv of sq replaces two).
// PASS 2: single field {|x-y|} into plane 0.
template<int R, int PASS>
DI void hconv2(const _Float16* __restrict__ src, _Float16* __restrict__ hb,
               const unsigned* __restrict__ E, const unsigned* __restrict__ O,
               int tid) {
  constexpr int NR = 32 + 2 * R;           // rows produced: [16-R, 48+R)
  constexpr int NG = NR * 8;               // 8 col-octets
  for (int g = tid; g < NG; g += 256) {
    const int row = (16 - R) + (g % NR);
    const int c0 = (g / NR) * 8;
    const int pbase = (c0 + 16 - R) >> 1;  // even
    const _Float16* px = src + row * PA + 2 * pbase;
    float a[8], b[8];
#pragma unroll
    for (int i = 0; i < 8; ++i) { a[i] = 0.f; b[i] = 0.f; }
#pragma unroll
    for (int p = 0; p < R + 4; ++p) {
      h2_t v0, v1;
      if (PASS == 0) {
        v0 = ldh2(px + 2 * p);             // x
        v1 = ldh2(px + 2 * p + TILE);      // y
      } else if (PASS == 1) {
        h2_t xq = ldh2(px + 2 * p);
        h2_t yq = ldh2(px + 2 * p + TILE);
        v0 = xq * xq + yq * yq;            // sq (pk mul + pk fma)
        v1 = xq * yq;                      // xy
      } else {
        h2_t xq = ldh2(px + 2 * p);
        h2_t yq = ldh2(px + 2 * p + TILE);
        v0 = pkabs(xq - yq);
      }
#pragma unroll
      for (int i = 0; i < 4; ++i) {
        const int j = p - i;
        if (j >= 0 && j <= R) {            // folds at compile time
          a[2 * i]     = fdot2f(w2h(E[j]), v0, a[2 * i]);
          a[2 * i + 1] = fdot2f(w2h(O[j]), v0, a[2 * i + 1]);
          if (PASS < 2) {
            b[2 * i]     = fdot2f(w2h(E[j]), v1, b[2 * i]);
            b[2 * i + 1] = fdot2f(w2h(O[j]), v1, b[2 * i + 1]);
          }
        }
      }
      if (PASS < 2) { if ((p & 3) == 3) SCHED_FENCE(); }
      else          { if ((p & 7) == 7) SCHED_FENCE(); }
    }
    _Float16* wp = hb + c0 * PB + row;     // hb[col][row]
#pragma unroll
    for (int i = 0; i < 8; ++i) {
      wp[i * PB] = (_Float16)a[i];
      if (PASS < 2) wp[i * PB + PLANE] = (_Float16)b[i];
    }
  }
}

// ---- vertical conv, both planes at once: 1 col x 8 rows [r0, r0+8) ----
// col = tid&63 spreads banks (33 dwords coprime 32).
template<int R>
DI void vconv2(const _Float16* __restrict__ hb,
               const unsigned* __restrict__ E, const unsigned* __restrict__ O,
               int col, int r0, float* __restrict__ a, float* __restrict__ b) {
  const int prow = (r0 + 16 - R) >> 1;
  const _Float16* p0 = hb + col * PB + 2 * prow;
#pragma unroll
  for (int p = 0; p < R + 4; ++p) {
    h2_t v0 = ldh2(p0 + 2 * p);
    h2_t v1 = ldh2(p0 + 2 * p + PLANE);
#pragma unroll
    for (int i = 0; i < 4; ++i) {
      const int j = p - i;
      if (j >= 0 && j <= R) {
        a[2 * i]     = fdot2f(w2h(E[j]), v0, a[2 * i]);
        a[2 * i + 1] = fdot2f(w2h(O[j]), v0, a[2 * i + 1]);
        b[2 * i]     = fdot2f(w2h(E[j]), v1, b[2 * i]);
        b[2 * i + 1] = fdot2f(w2h(O[j]), v1, b[2 * i + 1]);
      }
    }
    if ((p & 3) == 3) SCHED_FENCE();
  }
}

// ---- vertical conv of |x-y| collapsed to scalar via single uniform U ----
template<int R>
DI float vl1(const _Float16* __restrict__ hb, const unsigned* __restrict__ U,
             int col, int r0) {
  const int prow = (r0 + 16 - R) >> 1;
  const _Float16* p0 = hb + col * PB + 2 * prow;
  float s = 0.f;
#pragma unroll
  for (int p = 0; p < R + 4; ++p)
    s = fdot2f(w2h(U[p]), ldh2(p0 + 2 * p), s);
  return s;
}

// Per sigma: {x,y} h|bar|v|bar then {sq,xy} h|bar|v|bar -> 4 barriers
// (was 10-12), all stats live in registers for the elementwise fold.
template<int R, bool LAST>
DI void do_sigma(int sidx, const unsigned* __restrict__ tabs0,
                 const _Float16* __restrict__ xt, _Float16* __restrict__ hb,
                 float* __restrict__ PIcs, float& gl1s, int tid) {
  const unsigned* E = tabs0 + sidx * 64;
  const unsigned* O = E + 32;
  const int col = tid & 63, r0 = (tid >> 6) * 8;

  float mux[8], muy[8];
#pragma unroll
  for (int i = 0; i < 8; ++i) { mux[i] = 0.f; muy[i] = 0.f; }

  hconv2<R, 0>(xt, hb, E, O, tid);         // h(x) -> p0, h(y) -> p1
  __syncthreads();
  vconv2<R>(hb, E, O, col, r0, mux, muy);
  __syncthreads();
  hconv2<R, 1>(xt, hb, E, O, tid);         // h(x^2+y^2) -> p0, h(xy) -> p1
  __syncthreads();
  float s2[8], exy[8];
#pragma unroll
  for (int i = 0; i < 8; ++i) { s2[i] = 0.f; exy[i] = 0.f; }
  vconv2<R>(hb, E, O, col, r0, s2, exy);
  __syncthreads();
#pragma unroll
  for (int i = 0; i < 8; ++i) {
    float a = mux[i], bb = muy[i];
    float m2 = a * a + bb * bb;
    float mxy = a * bb;
    PIcs[i] *= fmaf(2.f, exy[i] - mxy, kC2) * rcp_fast(s2[i] - m2 + kC2);
    if (LAST)                              // luminance folded into PIcs
      PIcs[i] *= fmaf(2.f, mxy, kC1) * rcp_fast(m2 + kC1);
  }
  if (LAST) {
    hconv2<R, 2>(xt, hb, E, O, tid);       // h(|x-y|) -> p0
    __syncthreads();
    gl1s += vl1<R>(hb, tabs0 + 320, col, r0);
    __syncthreads();
  }
}

DI unsigned packh(float a, float b) {
  h2_t v; v.x = (_Float16)a; v.y = (_Float16)b;
  return __builtin_bit_cast(unsigned, v);
}

// ws: [0..164] f32 1D kernels; u32 tabs at +165: per sigma s: E @s*64+[0..R],
// O @s*64+32+[0..R]; single l1-collapse U table (R=16) @320+[0..19].
__global__ void prep_k(const float* __restrict__ gm, float* __restrict__ ws) {
  int t = threadIdx.x;
  if (t < 165) {
    int s = t / 33, j = t % 33;
    const float* m = gm + (3 * s) * (33 * 33);
    ws[t] = m[16 * 33 + j] / sqrtf(m[16 * 33 + 16]);
  }
  __syncthreads();
  if (t == 0) {
    unsigned* tabs = (unsigned*)(ws + 165);
    const int Rs[5] = {4, 6, 12, 16, 16};
    for (int s = 0; s < 5; ++s) {
      const int R = Rs[s];
      const float* w = ws + s * 33 + (16 - R);   // K = 2R+1 taps
      unsigned* E = tabs + s * 64;
      unsigned* O = E + 32;
      for (int i = 0; i < R; ++i) E[i] = packh(w[2 * i], w[2 * i + 1]);
      E[R] = packh(w[2 * R], 0.f);
      O[0] = packh(0.f, w[0]);
      for (int i = 1; i <= R; ++i) O[i] = packh(w[2 * i - 1], w[2 * i]);
    }
    // U[p] = sum over i=0..3, j=p-i in [0,16] of (E[j]+O[j]), sigma=8 (R=16)
    const float* w = ws + 4 * 33;
    unsigned* U = tabs + 320;
    for (int p = 0; p < 20; ++p) {
      float ux = 0.f, uy = 0.f;
      for (int i = 0; i < 4; ++i) {
        int j = p - i;
        if (j < 0 || j > 16) continue;
        ux += w[2 * j];                          // E[j].x
        if (2 * j + 1 <= 32) uy += w[2 * j + 1]; // E[j].y
        if (j > 0) ux += w[2 * j - 1];           // O[j].x
        uy += w[2 * j];                          // O[j].y
      }
      U[p] = packh(ux, uy);
    }
  }
}

// 64x32 output tile, 41 KB LDS -> 3 blocks/CU. (256,3) -> VGPR cap ~168.
__global__ __launch_bounds__(256, 3)
void msloss_k(const float* __restrict__ x, const float* __restrict__ y,
              const float* __restrict__ ws, float* __restrict__ out) {
  // xt @0 [row][col] (64x96), yt @TILE, hb @2*TILE: 2 planes [col][row] 64x64
  __shared__ __align__(16) _Float16 smem[2 * TILE + 2 * PLANE];
  __shared__ float red[4];
  _Float16* xt = smem;
  _Float16* hb = smem + 2 * TILE;
  const unsigned* tabs0 = (const unsigned*)(ws + 165);
  const int tid = threadIdx.x;
  const int ox = blockIdx.x * 64, oy = blockIdx.y * 32;
  const int b = blockIdx.z;

  float PIcs[8];
  float gl1s = 0.f;
#pragma unroll
  for (int i = 0; i < 8; ++i) PIcs[i] = 1.f;

  for (int c = 0; c < 3; ++c) {
    const float* xp = x + (size_t)(b * 3 + c) * (512 * 512);
    const float* yp = y + (size_t)(b * 3 + c) * (512 * 512);
    // stage 64 rows x 96 cols fp32 -> fp16, [row][col], zero halo
#pragma unroll
    for (int it = 0; it < 12; ++it) {
      int idx = it * 256 + tid;            // 64 rows x 48 colpairs
      int row = idx / 48, cp = idx % 48;
      int gy = oy + row - 16, gx = ox + cp * 2 - 16;
      bool ok = ((unsigned)gy < 512u) && ((unsigned)gx < 512u);  // gx even
      float2 xv = make_float2(0.f, 0.f), yv = make_float2(0.f, 0.f);
      if (ok) {
        xv = *reinterpret_cast<const float2*>(xp + gy * 512 + gx);
        yv = *reinterpret_cast<const float2*>(yp + gy * 512 + gx);
      }
      h2_t hx; hx.x = (_Float16)xv.x; hx.y = (_Float16)xv.y;
      h2_t hy; hy.x = (_Float16)yv.x; hy.y = (_Float16)yv.y;
      *reinterpret_cast<h2_t*>(xt + row * PA + cp * 2) = hx;
      *reinterpret_cast<h2_t*>(xt + TILE + row * PA + cp * 2) = hy;
    }
    __syncthreads();
    do_sigma<4,  false>(0, tabs0, xt, hb, PIcs, gl1s, tid);
    do_sigma<6,  false>(1, tabs0, xt, hb, PIcs, gl1s, tid);
    do_sigma<12, false>(2, tabs0, xt, hb, PIcs, gl1s, tid);
    do_sigma<16, false>(3, tabs0, xt, hb, PIcs, gl1s, tid);
    do_sigma<16, true >(4, tabs0, xt, hb, PIcs, gl1s, tid);
    // do_sigma ends with __syncthreads(): safe to restage next channel
  }

  float s = ((1.f - kALPHA) / 3.f) * gl1s;
#pragma unroll
  for (int i = 0; i < 8; ++i) s += kALPHA * (1.f - PIcs[i]);
#pragma unroll
  for (int off = 32; off > 0; off >>= 1) s += __shfl_down(s, off);
  if ((tid & 63) == 0) red[tid >> 6] = s;
  __syncthreads();
  if (tid == 0)
    atomicAdd(out, (red[0] + red[1] + red[2] + red[3]) *
                       (200.0f / (8.0f * 512.0f * 512.0f)));
}

extern "C" void kernel_launch(void* const* d_in, const int* in_sizes, int n_in,
                              void* d_out, int out_size, void* d_ws, size_t ws_size,
                              hipStream_t stream) {
  const float* x = (const float*)d_in[0];
  const float* y = (const float*)d_in[1];
  const float* gm = (const float*)d_in[2];
  float* out = (float*)d_out;
  float* ws = (float*)d_ws;   // 165 f32 + packed half2 tables (~1.6 KB)

  hipMemsetAsync(d_out, 0, out_size * sizeof(float), stream);
  prep_k<<<1, 256, 0, stream>>>(gm, ws);
  msloss_k<<<dim3(8, 16, 8), 256, 0, stream>>>(x, y, ws, out);
}

// Round 3
// 307.175 us; speedup vs baseline: 1.4177x; 1.2004x over previous
//
#include <hip/hip_runtime.h>

typedef _Float16 h2_t __attribute__((ext_vector_type(2)));
typedef _Float16 f16x8 __attribute__((ext_vector_type(8)));
typedef float f32x4 __attribute__((ext_vector_type(4)));
typedef unsigned u32x4 __attribute__((ext_vector_type(4)));

#define DI __device__ __forceinline__

constexpr int PAW = 96;          // xt pitch (halfs): 192 B rows, 16B-aligned + XOR swizzle
constexpr int PBV = 72;          // hb pitch (halfs): 144 B rows = 9*16 -> b128-aligned, odd slot stride
constexpr int TILE = 64 * PAW;   // one staged image plane: 6144 halfs
constexpr int PLANE = 64 * PBV;  // one hb plane: 4608 halfs
constexpr float kC1 = 1.0e-4f;   // (0.01*1)^2
constexpr float kC2 = 9.0e-4f;   // (0.03*1)^2
constexpr float kALPHA = 0.025f;

DI float rcp_fast(float v) { return __builtin_amdgcn_rcpf(v); }

DI float fdot2f(h2_t a, h2_t b, float c) {
#if __has_builtin(__builtin_amdgcn_fdot2)
  return __builtin_amdgcn_fdot2(a, b, c, false);   // v_dot2_f32_f16
#else
  return c + (float)(a.x) * (float)(b.x) + (float)(a.y) * (float)(b.y);
#endif
}

DI h2_t w2h(unsigned u) { return __builtin_bit_cast(h2_t, u); }

DI f16x8 ldfrag(const _Float16* __restrict__ p) {
  return *reinterpret_cast<const f16x8*>(p);
}

DI f32x4 mfma16(f16x8 a, f16x8 b, f32x4 c) {
  return __builtin_amdgcn_mfma_f32_16x16x32_f16(a, b, c, 0, 0, 0);
}

DI f16x8 pkabs8(f16x8 v) {
  u32x4 u = __builtin_bit_cast(u32x4, v);
  u32x4 msk = {0x7FFF7FFFu, 0x7FFF7FFFu, 0x7FFF7FFFu, 0x7FFF7FFFu};
  u &= msk;
  return __builtin_bit_cast(f16x8, u);
}

// ---- horizontal conv as MFMA: D[col][row] = Wh(banded) x xt^T ----
// A = weights (m = out-col), B = data fragments built from xt/yt in regs.
// Wave w owns out-cols [16w, 16w+16); band => k-tiles {0,32} (w<2) or {32,64}.
// PASS 0: {x, y} -> hb planes 0,1.  PASS 1: {x^2+y^2, x*y}.  PASS 2: {|x-y|} -> plane 0.
template<int PASS>
DI void hconv_m(const _Float16* __restrict__ xt, _Float16* __restrict__ hb,
                f16x8 wA0, f16x8 wA1, int w, int lane) {
  const int q = lane >> 4, m = lane & 15;
  const int K0b = (w < 2) ? 0 : 32;
  f32x4 zero4 = {0.f, 0.f, 0.f, 0.f};
  f32x4 a0[4], a1[4];
#pragma unroll
  for (int nt = 0; nt < 4; ++nt) { a0[nt] = zero4; a1[nt] = zero4; }
#pragma unroll
  for (int ks = 0; ks < 2; ++ks) {
    const f16x8 A = ks ? wA1 : wA0;
    const int K0 = K0b + ks * 32;
#pragma unroll
    for (int nt = 0; nt < 4; ++nt) {
      const int row = nt * 16 + m;
      const int idx = (row * PAW + K0 + q * 8) ^ ((row & 7) << 3);
      f16x8 xv = ldfrag(xt + idx);
      f16x8 yv = ldfrag(xt + TILE + idx);
      if (PASS == 0) {
        a0[nt] = mfma16(A, xv, a0[nt]);
        a1[nt] = mfma16(A, yv, a1[nt]);
      } else if (PASS == 1) {
        f16x8 sq = xv * xv + yv * yv;   // v_pk_mul/fma_f16
        f16x8 xy = xv * yv;
        a0[nt] = mfma16(A, sq, a0[nt]);
        a1[nt] = mfma16(A, xy, a1[nt]);
      } else {
        a0[nt] = mfma16(A, pkabs8(xv - yv), a0[nt]);
      }
    }
  }
  // C/D layout (m89-verified): m = (lane>>4)*4 + reg, n = lane&15.
  const int cb = w * 16 + q * 4;
#pragma unroll
  for (int nt = 0; nt < 4; ++nt)
#pragma unroll
    for (int j = 0; j < 4; ++j) {
      hb[(cb + j) * PBV + nt * 16 + m] = (_Float16)a0[nt][j];
      if (PASS < 2) hb[PLANE + (cb + j) * PBV + nt * 16 + m] = (_Float16)a1[nt][j];
    }
}

// ---- vertical conv as MFMA: D[col][or] = hb x Wv^T, both planes at once ----
// A = hb data (m = col, contiguous b128 along rows), B = weight frags (n = out-row).
DI void vconv_m(const _Float16* __restrict__ hb,
                f16x8 w00, f16x8 w01, f16x8 w10, f16x8 w11,
                int w, int lane, float* __restrict__ o0, float* __restrict__ o1) {
  const int q = lane >> 4, m = lane & 15;
  const int base = (w * 16 + m) * PBV + q * 8;
  f32x4 zero4 = {0.f, 0.f, 0.f, 0.f};
  f32x4 a00 = zero4, a01 = zero4, a10 = zero4, a11 = zero4;
#pragma unroll
  for (int ks = 0; ks < 2; ++ks) {
    f16x8 A0 = ldfrag(hb + base + ks * 32);
    f16x8 A1 = ldfrag(hb + PLANE + base + ks * 32);
    f16x8 B0 = ks ? w01 : w00;
    f16x8 B1 = ks ? w11 : w10;
    a00 = mfma16(A0, B0, a00);
    a01 = mfma16(A0, B1, a01);
    a10 = mfma16(A1, B0, a10);
    a11 = mfma16(A1, B1, a11);
  }
#pragma unroll
  for (int j = 0; j < 4; ++j) {
    o0[j] = a00[j]; o0[4 + j] = a01[j];
    o1[j] = a10[j]; o1[4 + j] = a11[j];
  }
}

// ---- vertical conv of |x-y| collapsed to scalar via single uniform U (R=16) ----
DI float vl1(const _Float16* __restrict__ hb, const unsigned* __restrict__ U,
             int col, int r0) {
  const _Float16* p0 = hb + col * PBV + r0;   // prow = r0>>1, 2*prow = r0
  float s = 0.f;
#pragma unroll
  for (int p = 0; p < 20; ++p)
    s = fdot2f(w2h(U[p]), *reinterpret_cast<const h2_t*>(p0 + 2 * p), s);
  return s;
}

// Per sigma: P0 | bar | vconv | bar | P1 | bar | vconv | bar | fold  (+ L1 on LAST).
template<bool LAST>
DI void do_sigma_m(int s, const _Float16* __restrict__ frh,
                   const unsigned* __restrict__ U,
                   const _Float16* __restrict__ xt, _Float16* __restrict__ hb,
                   float* __restrict__ PIcs, float& gl1s, int tid) {
  const int lane = tid & 63, w = tid >> 6;
  // weight frags [s][cls][ks][lane][8h]: shared between hconv (cls = w&1) and
  // vconv (cls = nt) because Delta0 = 32ks - 16cls in both derivations.
  const f16x8* fr = reinterpret_cast<const f16x8*>(frh) + s * 256 + lane;
  f16x8 w00 = fr[0], w01 = fr[64], w10 = fr[128], w11 = fr[192];
  const bool odd = (w & 1);
  f16x8 wA0 = odd ? w10 : w00;
  f16x8 wA1 = odd ? w11 : w01;

  hconv_m<0>(xt, hb, wA0, wA1, w, lane);
  __syncthreads();
  float mux[8], muy[8];
  vconv_m(hb, w00, w01, w10, w11, w, lane, mux, muy);
  __syncthreads();
  hconv_m<1>(xt, hb, wA0, wA1, w, lane);
  __syncthreads();
  float s2[8], exy[8];
  vconv_m(hb, w00, w01, w10, w11, w, lane, s2, exy);
  __syncthreads();
#pragma unroll
  for (int i = 0; i < 8; ++i) {
    float a = mux[i], b = muy[i];
    float m2 = a * a + b * b, mxy = a * b;
    PIcs[i] *= fmaf(2.f, exy[i] - mxy, kC2) * rcp_fast(s2[i] - m2 + kC2);
    if (LAST)                              // luminance folded into PIcs
      PIcs[i] *= fmaf(2.f, mxy, kC1) * rcp_fast(m2 + kC1);
  }
  if (LAST) {
    hconv_m<2>(xt, hb, wA0, wA1, w, lane);
    __syncthreads();
    gl1s += vl1(hb, U, tid & 63, (tid >> 6) * 8);
    __syncthreads();
  }
}

DI unsigned packh(float a, float b) {
  h2_t v; v.x = (_Float16)a; v.y = (_Float16)b;
  return __builtin_bit_cast(unsigned, v);
}

// ws layout (floats): [0..164] f32 1D kernels; u32 U[20] @168; weight frags
// (halfs) @208: [sigma][cls][ks][lane][8] = 10240 halfs (~20 KB).
__global__ void prep_k(const float* __restrict__ gm, float* __restrict__ ws) {
  int t = threadIdx.x;
  if (t < 165) {
    int s = t / 33, j = t % 33;
    const float* mk = gm + (3 * s) * (33 * 33);
    ws[t] = mk[16 * 33 + j] / sqrtf(mk[16 * 33 + 16]);
  }
  __syncthreads();
  if (t == 0) {
    // U[p] = sum over i=0..3, j=p-i in [0,16] of (E[j]+O[j]) halves, sigma=8
    const float* w = ws + 4 * 33;
    unsigned* U = (unsigned*)(ws + 168);
    for (int p = 0; p < 20; ++p) {
      float ux = 0.f, uy = 0.f;
      for (int i = 0; i < 4; ++i) {
        int j = p - i;
        if (j < 0 || j > 16) continue;
        ux += w[2 * j];
        if (2 * j + 1 <= 32) uy += w[2 * j + 1];
        if (j > 0) ux += w[2 * j - 1];
        uy += w[2 * j];
      }
      U[p] = packh(ux, uy);
    }
  }
  // weight fragments; k-map k = K0 + 8*(lane>>4) + i applied identically to the
  // data-operand reads, so any bijective mis-guess of the HW k-map cancels.
  _Float16* fr = (_Float16*)(ws + 208);
  const int Rs[5] = {4, 6, 12, 16, 16};
  for (int e = t; e < 10240; e += 256) {
    int s = e >> 11, r = e & 2047;
    int cls = (r >> 10) & 1, ks = (r >> 9) & 1, lane = (r >> 3) & 63, i = r & 7;
    int tp = 32 * ks - 16 * cls + 8 * (lane >> 4) + i - (lane & 15);
    int R = Rs[s], j = tp - 16 + R;
    float v = (j >= 0 && j <= 2 * R) ? ws[s * 33 + j] : 0.f;
    fr[e] = (_Float16)v;
  }
}

// 64x32 output tile, 43 KB LDS -> 3 blocks/CU (LDS-capped). (256,2): no VGPR
// squeeze -> avoids the R1 stat-array scratch spill (84-VGPR / +260 MB HBM).
__global__ __launch_bounds__(256, 2)
void msloss_k(const float* __restrict__ x, const float* __restrict__ y,
              const float* __restrict__ ws, float* __restrict__ out) {
  // xt @0 [row][col] swizzled (64x96), yt @TILE, hb @2*TILE: 2 planes [col][row]
  __shared__ __align__(16) _Float16 smem[2 * TILE + 2 * PLANE];
  __shared__ float red[4];
  _Float16* xt = smem;
  _Float16* hb = smem + 2 * TILE;
  const _Float16* frh = (const _Float16*)(ws + 208);
  const unsigned* U = (const unsigned*)(ws + 168);
  const int tid = threadIdx.x;
  const int ox = blockIdx.x * 64, oy = blockIdx.y * 32;
  const int b = blockIdx.z;

  float PIcs[8];
  float gl1s = 0.f;
#pragma unroll
  for (int i = 0; i < 8; ++i) PIcs[i] = 1.f;

  for (int c = 0; c < 3; ++c) {
    const float* xp = x + (size_t)(b * 3 + c) * (512 * 512);
    const float* yp = y + (size_t)(b * 3 + c) * (512 * 512);
    // stage 64 rows x 96 cols fp32 -> fp16, swizzled [row][col], zero halo
#pragma unroll
    for (int it = 0; it < 12; ++it) {
      int idx = it * 256 + tid;            // 64 rows x 48 colpairs
      int row = idx / 48, cp = idx % 48;
      int gy = oy + row - 16, gx = ox + cp * 2 - 16;
      bool ok = ((unsigned)gy < 512u) && ((unsigned)gx < 512u);  // gx even
      float2 xv = make_float2(0.f, 0.f), yv = make_float2(0.f, 0.f);
      if (ok) {
        xv = *reinterpret_cast<const float2*>(xp + gy * 512 + gx);
        yv = *reinterpret_cast<const float2*>(yp + gy * 512 + gx);
      }
      h2_t hx; hx.x = (_Float16)xv.x; hx.y = (_Float16)xv.y;
      h2_t hy; hy.x = (_Float16)yv.x; hy.y = (_Float16)yv.y;
      int si = (row * PAW + cp * 2) ^ ((row & 7) << 3);   // h2-safe: XOR bits>=3
      *reinterpret_cast<h2_t*>(xt + si) = hx;
      *reinterpret_cast<h2_t*>(xt + TILE + si) = hy;
    }
    __syncthreads();
    do_sigma_m<false>(0, frh, U, xt, hb, PIcs, gl1s, tid);
    do_sigma_m<false>(1, frh, U, xt, hb, PIcs, gl1s, tid);
    do_sigma_m<false>(2, frh, U, xt, hb, PIcs, gl1s, tid);
    do_sigma_m<false>(3, frh, U, xt, hb, PIcs, gl1s, tid);
    do_sigma_m<true >(4, frh, U, xt, hb, PIcs, gl1s, tid);
    // do_sigma ends with __syncthreads(): safe to restage next channel
  }

  float s = ((1.f - kALPHA) / 3.f) * gl1s;
#pragma unroll
  for (int i = 0; i < 8; ++i) s += kALPHA * (1.f - PIcs[i]);
#pragma unroll
  for (int off = 32; off > 0; off >>= 1) s += __shfl_down(s, off);
  if ((tid & 63) == 0) red[tid >> 6] = s;
  __syncthreads();
  if (tid == 0)
    atomicAdd(out, (red[0] + red[1] + red[2] + red[3]) *
                       (200.0f / (8.0f * 512.0f * 512.0f)));
}

extern "C" void kernel_launch(void* const* d_in, const int* in_sizes, int n_in,
                              void* d_out, int out_size, void* d_ws, size_t ws_size,
                              hipStream_t stream) {
  const float* x = (const float*)d_in[0];
  const float* y = (const float*)d_in[1];
  const float* gm = (const float*)d_in[2];
  float* out = (float*)d_out;
  float* ws = (float*)d_ws;   // 165 f32 + U + 20 KB weight frags

  hipMemsetAsync(d_out, 0, out_size * sizeof(float), stream);
  prep_k<<<1, 256, 0, stream>>>(gm, ws);
  msloss_k<<<dim3(8, 16, 8), 256, 0, stream>>>(x, y, ws, out);
}

// Round 4
// 289.845 us; speedup vs baseline: 1.5025x; 1.0598x over previous
//
#include <hip/hip_runtime.h>

typedef _Float16 h2_t __attribute__((ext_vector_type(2)));
typedef _Float16 f16x8 __attribute__((ext_vector_type(8)));
typedef float f32x4 __attribute__((ext_vector_type(4)));
typedef unsigned u32x4 __attribute__((ext_vector_type(4)));

#define DI __device__ __forceinline__

#if __has_builtin(__builtin_amdgcn_sched_barrier)
#define SCHED_FENCE() __builtin_amdgcn_sched_barrier(0)
#else
#define SCHED_FENCE()
#endif

constexpr int PAW = 96;          // xt pitch (halfs): 192 B rows, 16B-aligned + XOR swizzle
constexpr int PBV = 72;          // hb pitch (halfs): 144 B rows = 9*16 -> b128-aligned
constexpr int TILE = 64 * PAW;   // one staged image plane: 6144 halfs
constexpr int PLANE = 64 * PBV;  // one hb plane: 4608 halfs
constexpr float kC1 = 1.0e-4f;   // (0.01*1)^2
constexpr float kC2 = 9.0e-4f;   // (0.03*1)^2
constexpr float kALPHA = 0.025f;

DI float rcp_fast(float v) { return __builtin_amdgcn_rcpf(v); }

DI float fdot2f(h2_t a, h2_t b, float c) {
#if __has_builtin(__builtin_amdgcn_fdot2)
  return __builtin_amdgcn_fdot2(a, b, c, false);   // v_dot2_f32_f16
#else
  return c + (float)(a.x) * (float)(b.x) + (float)(a.y) * (float)(b.y);
#endif
}

DI h2_t w2h(unsigned u) { return __builtin_bit_cast(h2_t, u); }

DI f16x8 ldfrag(const _Float16* __restrict__ p) {
  return *reinterpret_cast<const f16x8*>(p);
}

DI f32x4 mfma16(f16x8 a, f16x8 b, f32x4 c) {
  return __builtin_amdgcn_mfma_f32_16x16x32_f16(a, b, c, 0, 0, 0);
}

DI f16x8 pkabs8(f16x8 v) {
  u32x4 u = __builtin_bit_cast(u32x4, v);
  u32x4 msk = {0x7FFF7FFFu, 0x7FFF7FFFu, 0x7FFF7FFFu, 0x7FFF7FFFu};
  u &= msk;
  return __builtin_bit_cast(f16x8, u);
}

// ---- horizontal conv as MFMA: D[col][row] = Wh(banded) x xt^T ----
// A = weights (m = out-col), B = data fragments built from xt/yt in regs.
// Wave w owns out-cols [16w, 16w+16); band => k-tiles {0,32} (w<2) or {32,64}.
// PASS 0: {x, y} -> hb planes 0,1.  PASS 1: {x^2+y^2, x*y}.  PASS 2: {|x-y|}.
// nt is the OUTER loop with acc lifetime = one nt, store immediately, and a
// sched_barrier after each nt: stops LLVM hoisting all 16 ds_read_b128 pairs
// (128 VGPRs in flight) above the MFMA chain -- that blow-up spilled at the
// 256-VGPR cap and cost ~420 MB/launch of scratch HBM round-trip (R3 PMC).
template<int PASS>
DI void hconv_m(const _Float16* __restrict__ xt, _Float16* __restrict__ hb,
                f16x8 wA0, f16x8 wA1, int w, int lane) {
  const int q = lane >> 4, m = lane & 15;
  const int K0b = (w < 2) ? 0 : 32;
  const int cb = w * 16 + q * 4;
  f32x4 zero4 = {0.f, 0.f, 0.f, 0.f};
#pragma unroll
  for (int nt = 0; nt < 4; ++nt) {
    const int row = nt * 16 + m;
    const int base = row * PAW + K0b + q * 8;
    f32x4 a0 = zero4, a1 = zero4;
#pragma unroll
    for (int ks = 0; ks < 2; ++ks) {
      const f16x8 A = ks ? wA1 : wA0;
      const int idx = (base + ks * 32) ^ ((row & 7) << 3);
      f16x8 xv = ldfrag(xt + idx);
      f16x8 yv = ldfrag(xt + TILE + idx);
      if (PASS == 0) {
        a0 = mfma16(A, xv, a0);
        a1 = mfma16(A, yv, a1);
      } else if (PASS == 1) {
        f16x8 sq = xv * xv + yv * yv;   // v_pk_mul/fma_f16
        f16x8 xy = xv * yv;
        a0 = mfma16(A, sq, a0);
        a1 = mfma16(A, xy, a1);
      } else {
        a0 = mfma16(A, pkabs8(xv - yv), a0);
      }
    }
    // C/D layout (m89-verified): m = (lane>>4)*4 + reg, n = lane&15.
    _Float16* wp = hb + cb * PBV + nt * 16 + m;
#pragma unroll
    for (int j = 0; j < 4; ++j) {
      wp[j * PBV] = (_Float16)a0[j];
      if (PASS < 2) wp[PLANE + j * PBV] = (_Float16)a1[j];
    }
    SCHED_FENCE();
  }
}

// ---- vertical conv as MFMA: D[col][or] = hb x Wv^T, both planes at once ----
// A = hb data (m = col, contiguous b128 along rows), B = weight frags (n = out-row).
DI void vconv_m(const _Float16* __restrict__ hb,
                f16x8 w00, f16x8 w01, f16x8 w10, f16x8 w11,
                int w, int lane, float* __restrict__ o0, float* __restrict__ o1) {
  const int q = lane >> 4, m = lane & 15;
  const int base = (w * 16 + m) * PBV + q * 8;
  f32x4 zero4 = {0.f, 0.f, 0.f, 0.f};
  f32x4 a00 = zero4, a01 = zero4, a10 = zero4, a11 = zero4;
#pragma unroll
  for (int ks = 0; ks < 2; ++ks) {
    f16x8 A0 = ldfrag(hb + base + ks * 32);
    f16x8 A1 = ldfrag(hb + PLANE + base + ks * 32);
    f16x8 B0 = ks ? w01 : w00;
    f16x8 B1 = ks ? w11 : w10;
    a00 = mfma16(A0, B0, a00);
    a01 = mfma16(A0, B1, a01);
    a10 = mfma16(A1, B0, a10);
    a11 = mfma16(A1, B1, a11);
    SCHED_FENCE();
  }
#pragma unroll
  for (int j = 0; j < 4; ++j) {
    o0[j] = a00[j]; o0[4 + j] = a01[j];
    o1[j] = a10[j]; o1[4 + j] = a11[j];
  }
}

// ---- vertical conv of |x-y| collapsed to scalar via single uniform U (R=16) ----
DI float vl1(const _Float16* __restrict__ hb, const unsigned* __restrict__ U,
             int col, int r0) {
  const _Float16* p0 = hb + col * PBV + r0;   // prow = r0>>1, 2*prow = r0
  float s = 0.f;
#pragma unroll
  for (int p = 0; p < 20; ++p)
    s = fdot2f(w2h(U[p]), *reinterpret_cast<const h2_t*>(p0 + 2 * p), s);
  return s;
}

// Per sigma: P0 | bar | vconv | bar | P1 | bar | vconv | bar | fold  (+ L1 on LAST).
template<bool LAST>
DI void do_sigma_m(int s, const _Float16* __restrict__ frh,
                   const unsigned* __restrict__ U,
                   const _Float16* __restrict__ xt, _Float16* __restrict__ hb,
                   float* __restrict__ PIcs, float& gl1s, int tid) {
  const int lane = tid & 63, w = tid >> 6;
  // weight frags [s][cls][ks][lane][8h]: shared between hconv (cls = w&1) and
  // vconv (cls = nt) because Delta0 = 32ks - 16cls in both derivations.
  const f16x8* fr = reinterpret_cast<const f16x8*>(frh) + s * 256 + lane;
  f16x8 w00 = fr[0], w01 = fr[64], w10 = fr[128], w11 = fr[192];
  const bool odd = (w & 1);
  f16x8 wA0 = odd ? w10 : w00;
  f16x8 wA1 = odd ? w11 : w01;

  hconv_m<0>(xt, hb, wA0, wA1, w, lane);
  __syncthreads();
  float mux[8], muy[8];
  vconv_m(hb, w00, w01, w10, w11, w, lane, mux, muy);
  __syncthreads();
  hconv_m<1>(xt, hb, wA0, wA1, w, lane);
  __syncthreads();
  float s2[8], exy[8];
  vconv_m(hb, w00, w01, w10, w11, w, lane, s2, exy);
  __syncthreads();
#pragma unroll
  for (int i = 0; i < 8; ++i) {
    float a = mux[i], b = muy[i];
    float m2 = a * a + b * b, mxy = a * b;
    PIcs[i] *= fmaf(2.f, exy[i] - mxy, kC2) * rcp_fast(s2[i] - m2 + kC2);
    if (LAST)                              // luminance folded into PIcs
      PIcs[i] *= fmaf(2.f, mxy, kC1) * rcp_fast(m2 + kC1);
  }
  if (LAST) {
    hconv_m<2>(xt, hb, wA0, wA1, w, lane);
    __syncthreads();
    gl1s += vl1(hb, U, tid & 63, (tid >> 6) * 8);
    __syncthreads();
  }
}

DI unsigned packh(float a, float b) {
  h2_t v; v.x = (_Float16)a; v.y = (_Float16)b;
  return __builtin_bit_cast(unsigned, v);
}

// ws layout (floats): [0..164] f32 1D kernels; u32 U[20] @168; weight frags
// (halfs) @208: [sigma][cls][ks][lane][8] = 10240 halfs (~20 KB).
__global__ void prep_k(const float* __restrict__ gm, float* __restrict__ ws) {
  int t = threadIdx.x;
  if (t < 165) {
    int s = t / 33, j = t % 33;
    const float* mk = gm + (3 * s) * (33 * 33);
    ws[t] = mk[16 * 33 + j] / sqrtf(mk[16 * 33 + 16]);
  }
  __syncthreads();
  if (t == 0) {
    // U[p] = sum over i=0..3, j=p-i in [0,16] of (E[j]+O[j]) halves, sigma=8
    const float* w = ws + 4 * 33;
    unsigned* U = (unsigned*)(ws + 168);
    for (int p = 0; p < 20; ++p) {
      float ux = 0.f, uy = 0.f;
      for (int i = 0; i < 4; ++i) {
        int j = p - i;
        if (j < 0 || j > 16) continue;
        ux += w[2 * j];
        if (2 * j + 1 <= 32) uy += w[2 * j + 1];
        if (j > 0) ux += w[2 * j - 1];
        uy += w[2 * j];
      }
      U[p] = packh(ux, uy);
    }
  }
  // weight fragments; k-map k = K0 + 8*(lane>>4) + i applied identically to the
  // data-operand reads, so any bijective mis-guess of the HW k-map cancels.
  _Float16* fr = (_Float16*)(ws + 208);
  const int Rs[5] = {4, 6, 12, 16, 16};
  for (int e = t; e < 10240; e += 256) {
    int s = e >> 11, r = e & 2047;
    int cls = (r >> 10) & 1, ks = (r >> 9) & 1, lane = (r >> 3) & 63, i = r & 7;
    int tp = 32 * ks - 16 * cls + 8 * (lane >> 4) + i - (lane & 15);
    int R = Rs[s], j = tp - 16 + R;
    float v = (j >= 0 && j <= 2 * R) ? ws[s * 33 + j] : 0.f;
    fr[e] = (_Float16)v;
  }
}

// 64x32 output tile, 43 KB LDS -> 3 blocks/CU (LDS-capped). (256,2): 256-VGPR
// cap; with per-nt acc lifetimes + sched fences true pressure ~130 -> no spill.
__global__ __launch_bounds__(256, 2)
void msloss_k(const float* __restrict__ x, const float* __restrict__ y,
              const float* __restrict__ ws, float* __restrict__ out) {
  // xt @0 [row][col] swizzled (64x96), yt @TILE, hb @2*TILE: 2 planes [col][row]
  __shared__ __align__(16) _Float16 smem[2 * TILE + 2 * PLANE];
  __shared__ float red[4];
  _Float16* xt = smem;
  _Float16* hb = smem + 2 * TILE;
  const _Float16* frh = (const _Float16*)(ws + 208);
  const unsigned* U = (const unsigned*)(ws + 168);
  const int tid = threadIdx.x;
  const int ox = blockIdx.x * 64, oy = blockIdx.y * 32;
  const int b = blockIdx.z;

  float PIcs[8];
  float gl1s = 0.f;
#pragma unroll
  for (int i = 0; i < 8; ++i) PIcs[i] = 1.f;

  for (int c = 0; c < 3; ++c) {
    const float* xp = x + (size_t)(b * 3 + c) * (512 * 512);
    const float* yp = y + (size_t)(b * 3 + c) * (512 * 512);
    // stage 64 rows x 96 cols fp32 -> fp16, swizzled [row][col], zero halo
#pragma unroll
    for (int it = 0; it < 12; ++it) {
      int idx = it * 256 + tid;            // 64 rows x 48 colpairs
      int row = idx / 48, cp = idx % 48;
      int gy = oy + row - 16, gx = ox + cp * 2 - 16;
      bool ok = ((unsigned)gy < 512u) && ((unsigned)gx < 512u);  // gx even
      float2 xv = make_float2(0.f, 0.f), yv = make_float2(0.f, 0.f);
      if (ok) {
        xv = *reinterpret_cast<const float2*>(xp + gy * 512 + gx);
        yv = *reinterpret_cast<const float2*>(yp + gy * 512 + gx);
      }
      h2_t hx; hx.x = (_Float16)xv.x; hx.y = (_Float16)xv.y;
      h2_t hy; hy.x = (_Float16)yv.x; hy.y = (_Float16)yv.y;
      int si = (row * PAW + cp * 2) ^ ((row & 7) << 3);   // h2-safe: XOR bits>=3
      *reinterpret_cast<h2_t*>(xt + si) = hx;
      *reinterpret_cast<h2_t*>(xt + TILE + si) = hy;
    }
    __syncthreads();
    do_sigma_m<false>(0, frh, U, xt, hb, PIcs, gl1s, tid);
    do_sigma_m<false>(1, frh, U, xt, hb, PIcs, gl1s, tid);
    do_sigma_m<false>(2, frh, U, xt, hb, PIcs, gl1s, tid);
    do_sigma_m<false>(3, frh, U, xt, hb, PIcs, gl1s, tid);
    do_sigma_m<true >(4, frh, U, xt, hb, PIcs, gl1s, tid);
    // do_sigma ends with __syncthreads(): safe to restage next channel
  }

  float s = ((1.f - kALPHA) / 3.f) * gl1s;
#pragma unroll
  for (int i = 0; i < 8; ++i) s += kALPHA * (1.f - PIcs[i]);
#pragma unroll
  for (int off = 32; off > 0; off >>= 1) s += __shfl_down(s, off);
  if ((tid & 63) == 0) red[tid >> 6] = s;
  __syncthreads();
  if (tid == 0)
    atomicAdd(out, (red[0] + red[1] + red[2] + red[3]) *
                       (200.0f / (8.0f * 512.0f * 512.0f)));
}

extern "C" void kernel_launch(void* const* d_in, const int* in_sizes, int n_in,
                              void* d_out, int out_size, void* d_ws, size_t ws_size,
                              hipStream_t stream) {
  const float* x = (const float*)d_in[0];
  const float* y = (const float*)d_in[1];
  const float* gm = (const float*)d_in[2];
  float* out = (float*)d_out;
  float* ws = (float*)d_ws;   // 165 f32 + U + 20 KB weight frags

  hipMemsetAsync(d_out, 0, out_size * sizeof(float), stream);
  prep_k<<<1, 256, 0, stream>>>(gm, ws);
  msloss_k<<<dim3(8, 16, 8), 256, 0, stream>>>(x, y, ws, out);
}

// Round 8
// 275.762 us; speedup vs baseline: 1.5792x; 1.0511x over previous
//
#include <hip/hip_runtime.h>

typedef _Float16 h2_t __attribute__((ext_vector_type(2)));
typedef _Float16 f16x8 __attribute__((ext_vector_type(8)));
typedef float f32x4 __attribute__((ext_vector_type(4)));
typedef unsigned u32x4 __attribute__((ext_vector_type(4)));

#define DI __device__ __forceinline__

#if __has_builtin(__builtin_amdgcn_sched_barrier)
#define SCHED_FENCE() __builtin_amdgcn_sched_barrier(0)
#else
#define SCHED_FENCE()
#endif

constexpr int PAW = 96;          // xt pitch (halfs): 192 B rows, 16B-aligned + XOR swizzle
constexpr int PBV = 72;          // hb pitch (halfs): 144 B rows = 9*16 -> b128-aligned
constexpr int TILE = 64 * PAW;   // one staged image plane: 6144 halfs
constexpr int PLANE = 64 * PBV;  // one hb plane: 4608 halfs
constexpr float kC1 = 1.0e-4f;   // (0.01*1)^2
constexpr float kC2 = 9.0e-4f;   // (0.03*1)^2
constexpr float kALPHA = 0.025f;

DI float rcp_fast(float v) { return __builtin_amdgcn_rcpf(v); }

DI float fdot2f(h2_t a, h2_t b, float c) {
#if __has_builtin(__builtin_amdgcn_fdot2)
  return __builtin_amdgcn_fdot2(a, b, c, false);   // v_dot2_f32_f16
#else
  return c + (float)(a.x) * (float)(b.x) + (float)(a.y) * (float)(b.y);
#endif
}

DI h2_t w2h(unsigned u) { return __builtin_bit_cast(h2_t, u); }

DI f16x8 ldfrag(const _Float16* __restrict__ p) {
  return *reinterpret_cast<const f16x8*>(p);
}

DI f32x4 mfma16(f16x8 a, f16x8 b, f32x4 c) {
  return __builtin_amdgcn_mfma_f32_16x16x32_f16(a, b, c, 0, 0, 0);
}

DI f16x8 pkabs8(f16x8 v) {
  u32x4 u = __builtin_bit_cast(u32x4, v);
  u32x4 msk = {0x7FFF7FFFu, 0x7FFF7FFFu, 0x7FFF7FFFu, 0x7FFF7FFFu};
  u &= msk;
  return __builtin_bit_cast(f16x8, u);
}

// ---- fused horizontal conv as MFMA: all fields in ONE pass ----
// D[col][row] = Wh(banded) x field^T for field in {x, y, x^2+y^2, x*y (,|x-y|)}.
// One set of xt/yt fragment reads feeds 4-5 MFMA chains -> planes 0..3 (,4).
// nt outer, acc lifetime = one nt, store immediately + sched fence: keeps
// in-flight regs ~50 (R3's full-unroll hoisting spilled ~420 MB of scratch).
template<bool L1P>
DI void hconv_all(const _Float16* __restrict__ xt, _Float16* __restrict__ hb,
                  f16x8 wA0, f16x8 wA1, int w, int lane) {
  const int q = lane >> 4, m = lane & 15;
  const int K0b = (w < 2) ? 0 : 32;
  const int cb = w * 16 + q * 4;
  f32x4 zero4 = {0.f, 0.f, 0.f, 0.f};
#pragma unroll
  for (int nt = 0; nt < 4; ++nt) {
    const int row = nt * 16 + m;
    const int base = row * PAW + K0b + q * 8;
    f32x4 ax = zero4, ay = zero4, asq = zero4, axy = zero4, al1 = zero4;
#pragma unroll
    for (int ks = 0; ks < 2; ++ks) {
      const f16x8 A = ks ? wA1 : wA0;
      const int idx = (base + ks * 32) ^ ((row & 7) << 3);
      f16x8 xv = ldfrag(xt + idx);
      f16x8 yv = ldfrag(xt + TILE + idx);
      ax = mfma16(A, xv, ax);
      ay = mfma16(A, yv, ay);
      asq = mfma16(A, xv * xv + yv * yv, asq);   // v_pk_mul/fma_f16
      axy = mfma16(A, xv * yv, axy);
      if (L1P) al1 = mfma16(A, pkabs8(xv - yv), al1);
    }
    // C/D layout (m89-verified): m = (lane>>4)*4 + reg, n = lane&15.
    _Float16* wp = hb + cb * PBV + nt * 16 + m;
#pragma unroll
    for (int j = 0; j < 4; ++j) {
      wp[j * PBV] = (_Float16)ax[j];
      wp[PLANE + j * PBV] = (_Float16)ay[j];
      wp[2 * PLANE + j * PBV] = (_Float16)asq[j];
      wp[3 * PLANE + j * PBV] = (_Float16)axy[j];
      if (L1P) wp[4 * PLANE + j * PBV] = (_Float16)al1[j];
    }
    SCHED_FENCE();
  }
}

// ---- fused vertical conv: all 4 stat planes -> 8 f32x4 accumulators ----
// A = hb data (m = col, contiguous b128), B = weight frags (n = out-row 16-group).
// acc[2*pl + g]: plane pl, out-row group g. Stats live only in this region.
DI void vconv_all(const _Float16* __restrict__ hb,
                  f16x8 w00, f16x8 w01, f16x8 w10, f16x8 w11,
                  int w, int lane, f32x4* __restrict__ acc) {
  const int q = lane >> 4, m = lane & 15;
  const int base = (w * 16 + m) * PBV + q * 8;
#pragma unroll
  for (int ks = 0; ks < 2; ++ks) {
    f16x8 B0 = ks ? w01 : w00;
    f16x8 B1 = ks ? w11 : w10;
#pragma unroll
    for (int pl = 0; pl < 4; ++pl) {
      f16x8 A = ldfrag(hb + pl * PLANE + base + ks * 32);
      acc[2 * pl]     = mfma16(A, B0, acc[2 * pl]);
      acc[2 * pl + 1] = mfma16(A, B1, acc[2 * pl + 1]);
    }
    SCHED_FENCE();
  }
}

// ---- vertical conv of |x-y| (plane 4) collapsed to scalar via uniform U ----
DI float vl1(const _Float16* __restrict__ hb, const unsigned* __restrict__ U,
             int col, int r0) {
  const _Float16* p0 = hb + 4 * PLANE + col * PBV + r0;
  float s = 0.f;
#pragma unroll
  for (int p = 0; p < 20; ++p)
    s = fdot2f(w2h(U[p]), *reinterpret_cast<const h2_t*>(p0 + 2 * p), s);
  return s;
}

// Per sigma: hconv_all | bar | vconv_all + fold (+vl1) | bar.  Only PIcs[8] +
// gl1s (9 VGPRs) live across barriers -> no cross-region stat spill (R4's
// 117 MB WRITE_SIZE came from mux/muy/s2/exy living across hconv regions).
template<bool LAST>
DI void do_sigma_m(int s, const _Float16* __restrict__ frh,
                   const unsigned* __restrict__ U,
                   const _Float16* __restrict__ xt, _Float16* __restrict__ hb,
                   float* __restrict__ PIcs, float& gl1s, int tid) {
  const int lane = tid & 63, w = tid >> 6;
  // weight frags [s][cls][ks][lane][8h]: shared between hconv (cls = w&1) and
  // vconv (cls = out-row group) because Delta0 = 32ks - 16cls in both.
  const f16x8* fr = reinterpret_cast<const f16x8*>(frh) + s * 256 + lane;
  f16x8 w00 = fr[0], w01 = fr[64], w10 = fr[128], w11 = fr[192];
  const bool odd = (w & 1);
  f16x8 wA0 = odd ? w10 : w00;
  f16x8 wA1 = odd ? w11 : w01;

  hconv_all<LAST>(xt, hb, wA0, wA1, w, lane);
  __syncthreads();
  f32x4 zero4 = {0.f, 0.f, 0.f, 0.f};
  f32x4 acc[8];
#pragma unroll
  for (int i = 0; i < 8; ++i) acc[i] = zero4;
  vconv_all(hb, w00, w01, w10, w11, w, lane, acc);
  if (LAST) gl1s += vl1(hb, U, tid & 63, (tid >> 6) * 8);
  // fold: acc[0..1]=mux, [2..3]=muy, [4..5]=s2, [6..7]=exy (per row-group h)
#pragma unroll
  for (int h = 0; h < 2; ++h)
#pragma unroll
    for (int j = 0; j < 4; ++j) {
      const int i = h * 4 + j;
      float a = acc[h][j], b = acc[2 + h][j];
      float m2 = a * a + b * b, mxy = a * b;
      PIcs[i] *= fmaf(2.f, acc[6 + h][j] - mxy, kC2) *
                 rcp_fast(acc[4 + h][j] - m2 + kC2);
      if (LAST)                            // luminance folded into PIcs
        PIcs[i] *= fmaf(2.f, mxy, kC1) * rcp_fast(m2 + kC1);
    }
  __syncthreads();                         // hb free for next sigma/channel
}

DI unsigned packh(float a, float b) {
  h2_t v; v.x = (_Float16)a; v.y = (_Float16)b;
  return __builtin_bit_cast(unsigned, v);
}

// ws layout (floats): [0..164] f32 1D kernels; u32 U[20] @168; weight frags
// (halfs) @208: [sigma][cls][ks][lane][8] = 10240 halfs (~20 KB).
__global__ void prep_k(const float* __restrict__ gm, float* __restrict__ ws) {
  int t = threadIdx.x;
  if (t < 165) {
    int s = t / 33, j = t % 33;
    const float* mk = gm + (3 * s) * (33 * 33);
    ws[t] = mk[16 * 33 + j] / sqrtf(mk[16 * 33 + 16]);
  }
  __syncthreads();
  if (t == 0) {
    // U[p] = sum over i=0..3, j=p-i in [0,16] of (E[j]+O[j]) halves, sigma=8
    const float* w = ws + 4 * 33;
    unsigned* U = (unsigned*)(ws + 168);
    for (int p = 0; p < 20; ++p) {
      float ux = 0.f, uy = 0.f;
      for (int i = 0; i < 4; ++i) {
        int j = p - i;
        if (j < 0 || j > 16) continue;
        ux += w[2 * j];
        if (2 * j + 1 <= 32) uy += w[2 * j + 1];
        if (j > 0) ux += w[2 * j - 1];
        uy += w[2 * j];
      }
      U[p] = packh(ux, uy);
    }
  }
  // weight fragments; k-map k = K0 + 8*(lane>>4) + i applied identically to the
  // data-operand reads, so any bijective mis-guess of the HW k-map cancels.
  _Float16* fr = (_Float16*)(ws + 208);
  const int Rs[5] = {4, 6, 12, 16, 16};
  for (int e = t; e < 10240; e += 256) {
    int s = e >> 11, r = e & 2047;
    int cls = (r >> 10) & 1, ks = (r >> 9) & 1, lane = (r >> 3) & 63, i = r & 7;
    int tp = 32 * ks - 16 * cls + 8 * (lane >> 4) + i - (lane & 15);
    int R = Rs[s], j = tp - 16 + R;
    float v = (j >= 0 && j <= 2 * R) ? ws[s * 33 + j] : 0.f;
    fr[e] = (_Float16)v;
  }
}

// 64x32 output tile, 69 KB LDS -> 2 blocks/CU (= measured residency anyway).
// (256,2): 256-VGPR budget; true pressure ~110 -> no spill.
__global__ __launch_bounds__(256, 2)
void msloss_k(const float* __restrict__ x, const float* __restrict__ y,
              const float* __restrict__ ws, float* __restrict__ out) {
  // xt @0 [row][col] swizzled (64x96), yt @TILE, hb @2*TILE: 5 planes [col][row]
  __shared__ __align__(16) _Float16 smem[2 * TILE + 5 * PLANE];
  __shared__ float red[4];
  _Float16* xt = smem;
  _Float16* hb = smem + 2 * TILE;
  const _Float16* frh = (const _Float16*)(ws + 208);
  const unsigned* U = (const unsigned*)(ws + 168);
  const int tid = threadIdx.x;
  const int ox = blockIdx.x * 64, oy = blockIdx.y * 32;
  const int b = blockIdx.z;

  float PIcs[8];
  float gl1s = 0.f;
#pragma unroll
  for (int i = 0; i < 8; ++i) PIcs[i] = 1.f;

  for (int c = 0; c < 3; ++c) {
    const float* xp = x + (size_t)(b * 3 + c) * (512 * 512);
    const float* yp = y + (size_t)(b * 3 + c) * (512 * 512);
    // stage 64 rows x 96 cols fp32 -> fp16, swizzled [row][col], zero halo
#pragma unroll
    for (int it = 0; it < 12; ++it) {
      int idx = it * 256 + tid;            // 64 rows x 48 colpairs
      int row = idx / 48, cp = idx % 48;
      int gy = oy + row - 16, gx = ox + cp * 2 - 16;
      bool ok = ((unsigned)gy < 512u) && ((unsigned)gx < 512u);  // gx even
      float2 xv = make_float2(0.f, 0.f), yv = make_float2(0.f, 0.f);
      if (ok) {
        xv = *reinterpret_cast<const float2*>(xp + gy * 512 + gx);
        yv = *reinterpret_cast<const float2*>(yp + gy * 512 + gx);
      }
      h2_t hx; hx.x = (_Float16)xv.x; hx.y = (_Float16)xv.y;
      h2_t hy; hy.x = (_Float16)yv.x; hy.y = (_Float16)yv.y;
      int si = (row * PAW + cp * 2) ^ ((row & 7) << 3);   // h2-safe: XOR bits>=3
      *reinterpret_cast<h2_t*>(xt + si) = hx;
      *reinterpret_cast<h2_t*>(xt + TILE + si) = hy;
    }
    __syncthreads();
    do_sigma_m<false>(0, frh, U, xt, hb, PIcs, gl1s, tid);
    do_sigma_m<false>(1, frh, U, xt, hb, PIcs, gl1s, tid);
    do_sigma_m<false>(2, frh, U, xt, hb, PIcs, gl1s, tid);
    do_sigma_m<false>(3, frh, U, xt, hb, PIcs, gl1s, tid);
    do_sigma_m<true >(4, frh, U, xt, hb, PIcs, gl1s, tid);
    // do_sigma ends with __syncthreads(): safe to restage next channel
  }

  float s = ((1.f - kALPHA) / 3.f) * gl1s;
#pragma unroll
  for (int i = 0; i < 8; ++i) s += kALPHA * (1.f - PIcs[i]);
#pragma unroll
  for (int off = 32; off > 0; off >>= 1) s += __shfl_down(s, off);
  if ((tid & 63) == 0) red[tid >> 6] = s;
  __syncthreads();
  if (tid == 0)
    atomicAdd(out, (red[0] + red[1] + red[2] + red[3]) *
                       (200.0f / (8.0f * 512.0f * 512.0f)));
}

extern "C" void kernel_launch(void* const* d_in, const int* in_sizes, int n_in,
                              void* d_out, int out_size, void* d_ws, size_t ws_size,
                              hipStream_t stream) {
  const float* x = (const float*)d_in[0];
  const float* y = (const float*)d_in[1];
  const float* gm = (const float*)d_in[2];
  float* out = (float*)d_out;
  float* ws = (float*)d_ws;   // 165 f32 + U + 20 KB weight frags

  hipMemsetAsync(d_out, 0, out_size * sizeof(float), stream);
  prep_k<<<1, 256, 0, stream>>>(gm, ws);
  msloss_k<<<dim3(8, 16, 8), 256, 0, stream>>>(x, y, ws, out);
}